// Round 8
// baseline (253.322 us; speedup 1.0000x reference)
//
#include <hip/hip_runtime.h>
#include <math.h>

typedef unsigned int u32;
typedef __attribute__((ext_vector_type(4))) unsigned int uint4v;

// out[r][c] = h[r][c] * S[c][c], S diagonal +-1 (fp32) => XOR of fp32 sign bit.
//
// v9: software-pipelined persistent waves. Evidence ladder (apply us):
//   strided NT/NT <79 | contig NT/NT ~67 | contig NT/plain ~66 (best total
//   247.4) | plain loads +15us | 16-deep one-shot: no change.
// Remaining structural delta vs the 6.29 TB/s copy ubench: our blocks are
// ONE-SHOT (wave: load batch, wait, xor, drain stores, exit -> zero read
// issue during drain/teardown). v9 gives each wave a 2048-chunk contiguous
// span looped in 512-chunk batches, double-buffered: batch b+1 loads are
// issued BEFORE batch b's stores, so reads stay continuously in flight
// (compiler emits counted vmcnt for the decoupled deps; no barriers).
// Static buffer names (no runtime-indexed arrays -> no scratch).

__global__ __launch_bounds__(256) void parity_mask_kernel(
    const u32* __restrict__ S, u32* __restrict__ mask, int dim)
{
    const int c = blockIdx.x * blockDim.x + threadIdx.x;
    if (c < dim) mask[c] = S[(long long)c * dim + c] & 0x80000000u;
}

// Pipelined path: requires cpr % 512 == 0, span % 1024 == 0,
// n_chunks == (gridDim.x*4) * span. Wave gw owns [gw*span, (gw+1)*span).
__global__ __launch_bounds__(256) void parity_apply_pipe(
    const uint4v* __restrict__ hv,
    const uint4v* __restrict__ maskv,   // cpr sign-mask chunks (16 KB, L2-hit)
    uint4v* __restrict__ ov,
    int cpr,
    long long span)                     // chunks per wave, multiple of 1024
{
    const int lane = threadIdx.x & 63;
    const int wv   = threadIdx.x >> 6;
    const long long gw = (long long)blockIdx.x * 4 + wv;
    long long c = gw * span;
    const long long nb = span >> 9;     // 512-chunk batches (even, >= 2)

#define LOADM(M, base) do { const int mb_ = (int)((base) % cpr);            \
    _Pragma("unroll") for (int k = 0; k < 8; ++k)                           \
        M[k] = maskv[mb_ + lane + 64 * k]; } while (0)
#define LOADV(V, base) do {                                                  \
    _Pragma("unroll") for (int k = 0; k < 8; ++k)                           \
        V[k] = __builtin_nontemporal_load(&hv[(base) + lane + 64 * k]);     \
    } while (0)
#define STOREB(base, V, M) do {                                              \
    _Pragma("unroll") for (int k = 0; k < 8; ++k)                           \
        ov[(base) + lane + 64 * k] = V[k] ^ M[k]; } while (0)

    uint4v mA[8], vA[8], mB[8], vB[8];

    LOADM(mA, c); LOADV(vA, c);                       // prologue: batch 0
    for (long long b = 0; b + 2 < nb; b += 2) {
        LOADM(mB, c + 512); LOADV(vB, c + 512);       // issue b+1
        STOREB(c, vA, mA);                            // finish b
        LOADM(mA, c + 1024); LOADV(vA, c + 1024);     // issue b+2
        STOREB(c + 512, vB, mB);                      // finish b+1
        c += 1024;
    }
    LOADM(mB, c + 512); LOADV(vB, c + 512);           // epilogue: last pair
    STOREB(c, vA, mA);
    STOREB(c + 512, vB, mB);

#undef LOADM
#undef LOADV
#undef STOREB
}

// One-shot contiguous path (v8, proven ~66us): cpr%512==0, n_chunks%2048==0.
__global__ __launch_bounds__(256) void parity_apply_contig(
    const uint4v* __restrict__ hv,
    const uint4v* __restrict__ maskv,
    uint4v* __restrict__ ov,
    int cpr)
{
    const int t    = threadIdx.x;
    const int lane = t & 63;
    const int wv   = t >> 6;
    const long long base_w = (long long)blockIdx.x * 2048 + (long long)wv * 512;
    const int mb = (int)(base_w % cpr);

    uint4v m[8], v[8];
#pragma unroll
    for (int k = 0; k < 8; ++k)
        m[k] = maskv[mb + lane + 64 * k];
#pragma unroll
    for (int k = 0; k < 8; ++k)
        v[k] = __builtin_nontemporal_load(&hv[base_w + lane + 64 * k]);
#pragma unroll
    for (int k = 0; k < 8; ++k) v[k] ^= m[k];
#pragma unroll
    for (int k = 0; k < 8; ++k)
        ov[base_w + lane + 64 * k] = v[k];
}

// Generic path: strided batch-8 fast lane + grid-stride tail (NT/NT, R0).
__global__ __launch_bounds__(256) void parity_apply_kernel(
    const uint4v* __restrict__ hv,
    const uint4v* __restrict__ maskv,
    uint4v* __restrict__ ov,
    int cpr,
    long long n_chunks)
{
    const long long tid = (long long)blockIdx.x * blockDim.x + threadIdx.x;
    const long long s   = (long long)gridDim.x * blockDim.x;

    if ((s % cpr) == 0 && tid + 7 * s < n_chunks) {
        const uint4v m = maskv[(int)(tid % cpr)];
        uint4v v[8];
#pragma unroll
        for (int k = 0; k < 8; ++k)
            v[k] = __builtin_nontemporal_load(&hv[tid + k * s]);
#pragma unroll
        for (int k = 0; k < 8; ++k) v[k] ^= m;
#pragma unroll
        for (int k = 0; k < 8; ++k)
            __builtin_nontemporal_store(v[k], &ov[tid + k * s]);
    } else {
        for (long long i = tid; i < n_chunks; i += s) {
            uint4v m = maskv[(int)(i % cpr)];
            uint4v v = __builtin_nontemporal_load(&hv[i]);
            v ^= m;
            __builtin_nontemporal_store(v, &ov[i]);
        }
    }
}

// Fallback (ws too small): read S's diagonal directly.
__global__ __launch_bounds__(256) void parity_fallback_kernel(
    const u32* __restrict__ h, const u32* __restrict__ S, u32* __restrict__ out,
    int dim, long long n_chunks)
{
    const int cpr = dim >> 2;
    const long long tid    = (long long)blockIdx.x * blockDim.x + threadIdx.x;
    const long long stride = (long long)gridDim.x * blockDim.x;
    const uint4v* hv = (const uint4v*)h;
    uint4v* ov = (uint4v*)out;
    for (long long i = tid; i < n_chunks; i += stride) {
        const int c0 = (int)(i % cpr) * 4;
        uint4v v = hv[i];
#pragma unroll
        for (int j = 0; j < 4; ++j) {
            const long long c = c0 + j;
            v[j] ^= (S[c * (long long)dim + c] & 0x80000000u);
        }
        __builtin_nontemporal_store(v, &ov[i]);
    }
}

extern "C" void kernel_launch(void* const* d_in, const int* in_sizes, int n_in,
                              void* d_out, int out_size, void* d_ws, size_t ws_size,
                              hipStream_t stream) {
    (void)n_in; (void)out_size;
    const u32* h = (const u32*)d_in[0];
    const u32* S = (const u32*)d_in[1];
    u32* out = (u32*)d_out;

    const long long s_elems = (long long)in_sizes[1];
    const int dim = (int)llroundl(sqrtl((long double)s_elems));  // 4096
    const long long n = (long long)in_sizes[0];
    const long long n_chunks = n >> 2;        // 4 fp32 per 16B chunk
    const int cpr = dim >> 2;                 // 1024

    const int block = 256;
    if (ws_size >= (size_t)dim * sizeof(u32) && (dim & 3) == 0) {
        u32* mask = (u32*)d_ws;
        parity_mask_kernel<<<(dim + block - 1) / block, block, 0, stream>>>(
            S, mask, dim);

        // Pipelined path: pick total-wave count W so span = n_chunks/W is a
        // multiple of 1024. 8192x4096: W=4096 -> grid 1024, span 2048 (nb=4).
        long long Wsel = 0, span = 0;
        const long long Wcand[3] = {4096, 2048, 8192};
        for (int i = 0; i < 3; ++i) {
            const long long W = Wcand[i];
            if (n_chunks % W == 0 && ((n_chunks / W) & 1023) == 0) {
                Wsel = W; span = n_chunks / W; break;
            }
        }

        if ((cpr % 512) == 0 && Wsel > 0) {
            const int grid = (int)(Wsel / 4);   // 4 waves per block
            parity_apply_pipe<<<grid, block, 0, stream>>>(
                (const uint4v*)h, (const uint4v*)mask, (uint4v*)out, cpr, span);
        } else if ((cpr % 512) == 0 && (n_chunks % 2048) == 0 &&
                   (n_chunks / 2048) <= 0x7fffffffLL) {
            const long long grid = n_chunks / 2048;
            parity_apply_contig<<<(int)grid, block, 0, stream>>>(
                (const uint4v*)h, (const uint4v*)mask, (uint4v*)out, cpr);
        } else {
            long long grid = (n_chunks + (long long)block * 8 - 1) /
                             ((long long)block * 8);
            if (grid < 1) grid = 1;
            parity_apply_kernel<<<(int)grid, block, 0, stream>>>(
                (const uint4v*)h, (const uint4v*)mask, (uint4v*)out, cpr, n_chunks);
        }
    } else {
        int grid = 2048;
        if ((long long)grid * block > n_chunks) {
            grid = (int)((n_chunks + block - 1) / block);
            if (grid < 1) grid = 1;
        }
        parity_fallback_kernel<<<grid, block, 0, stream>>>(h, S, out, dim, n_chunks);
    }
}

// Round 9
// 249.418 us; speedup vs baseline: 1.0157x; 1.0157x over previous
//
#include <hip/hip_runtime.h>
#include <math.h>

typedef unsigned int u32;
typedef __attribute__((ext_vector_type(4))) unsigned int uint4v;

// out[r][c] = h[r][c] * S[c][c], S diagonal +-1 (fp32) => XOR of fp32 sign bit.
//
// v10 == v8 (measured argmax, 247.4 us total): NT loads + plain stores,
// wave-contiguous one-shot. Final lever table (apply-kernel us):
//   contiguity: strided->contig +12us (v5) | NT loads: +15us vs plain (R6)
//   store hint: neutral (2x2 matrix complete) | depth 8->16: neutral (v6)
//   persistent pipelined waves: -5us REGRESSION (v9) | scatter vs table: +8us
// Six structural variants converge at apply ~66-67us (4.1 TB/s logical,
// 3.0 TB/s HBM-side, FETCH stable at 66MB regardless of hints). Remaining
// gap vs the 6.3 TB/s copy ubench is environmental (512MiB poison fills
// precede each replay; ~180us of total is harness fill traffic at 84-86%
// of HBM peak). This is the ship config.

__global__ __launch_bounds__(256) void parity_mask_kernel(
    const u32* __restrict__ S, u32* __restrict__ mask, int dim)
{
    const int c = blockIdx.x * blockDim.x + threadIdx.x;
    if (c < dim) mask[c] = S[(long long)c * dim + c] & 0x80000000u;
}

// Fast path: requires n_chunks % 2048 == 0 and cpr % 512 == 0.
// Wave w of block b owns chunks [b*2048 + w*512, +512): contiguous 8 KB.
__global__ __launch_bounds__(256) void parity_apply_contig(
    const uint4v* __restrict__ hv,
    const uint4v* __restrict__ maskv,   // cpr sign-mask chunks (16 KB, L2-hit)
    uint4v* __restrict__ ov,
    int cpr)
{
    const int t    = threadIdx.x;
    const int lane = t & 63;
    const int wv   = t >> 6;
    const long long base_w = (long long)blockIdx.x * 2048 + (long long)wv * 512;
    const int mb = (int)(base_w % cpr);

    uint4v m[8], v[8];
#pragma unroll
    for (int k = 0; k < 8; ++k)
        m[k] = maskv[mb + lane + 64 * k];            // coalesced, L2-hit
#pragma unroll
    for (int k = 0; k < 8; ++k)
        v[k] = __builtin_nontemporal_load(&hv[base_w + lane + 64 * k]);  // NT
#pragma unroll
    for (int k = 0; k < 8; ++k) v[k] ^= m[k];
#pragma unroll
    for (int k = 0; k < 8; ++k)
        ov[base_w + lane + 64 * k] = v[k];           // plain cached store
}

// Generic path: strided batch-8 fast lane + grid-stride tail (NT/NT, R0).
__global__ __launch_bounds__(256) void parity_apply_kernel(
    const uint4v* __restrict__ hv,
    const uint4v* __restrict__ maskv,
    uint4v* __restrict__ ov,
    int cpr,
    long long n_chunks)
{
    const long long tid = (long long)blockIdx.x * blockDim.x + threadIdx.x;
    const long long s   = (long long)gridDim.x * blockDim.x;

    if ((s % cpr) == 0 && tid + 7 * s < n_chunks) {
        const uint4v m = maskv[(int)(tid % cpr)];
        uint4v v[8];
#pragma unroll
        for (int k = 0; k < 8; ++k)
            v[k] = __builtin_nontemporal_load(&hv[tid + k * s]);
#pragma unroll
        for (int k = 0; k < 8; ++k) v[k] ^= m;
#pragma unroll
        for (int k = 0; k < 8; ++k)
            __builtin_nontemporal_store(v[k], &ov[tid + k * s]);
    } else {
        for (long long i = tid; i < n_chunks; i += s) {
            uint4v m = maskv[(int)(i % cpr)];
            uint4v v = __builtin_nontemporal_load(&hv[i]);
            v ^= m;
            __builtin_nontemporal_store(v, &ov[i]);
        }
    }
}

// Fallback (ws too small): read S's diagonal directly.
__global__ __launch_bounds__(256) void parity_fallback_kernel(
    const u32* __restrict__ h, const u32* __restrict__ S, u32* __restrict__ out,
    int dim, long long n_chunks)
{
    const int cpr = dim >> 2;
    const long long tid    = (long long)blockIdx.x * blockDim.x + threadIdx.x;
    const long long stride = (long long)gridDim.x * blockDim.x;
    const uint4v* hv = (const uint4v*)h;
    uint4v* ov = (uint4v*)out;
    for (long long i = tid; i < n_chunks; i += stride) {
        const int c0 = (int)(i % cpr) * 4;
        uint4v v = hv[i];
#pragma unroll
        for (int j = 0; j < 4; ++j) {
            const long long c = c0 + j;
            v[j] ^= (S[c * (long long)dim + c] & 0x80000000u);
        }
        __builtin_nontemporal_store(v, &ov[i]);
    }
}

extern "C" void kernel_launch(void* const* d_in, const int* in_sizes, int n_in,
                              void* d_out, int out_size, void* d_ws, size_t ws_size,
                              hipStream_t stream) {
    (void)n_in; (void)out_size;
    const u32* h = (const u32*)d_in[0];
    const u32* S = (const u32*)d_in[1];
    u32* out = (u32*)d_out;

    const long long s_elems = (long long)in_sizes[1];
    const int dim = (int)llroundl(sqrtl((long double)s_elems));  // 4096
    const long long n = (long long)in_sizes[0];
    const long long n_chunks = n >> 2;        // 4 fp32 per 16B chunk
    const int cpr = dim >> 2;                 // 1024

    const int block = 256;
    if (ws_size >= (size_t)dim * sizeof(u32) && (dim & 3) == 0) {
        u32* mask = (u32*)d_ws;
        parity_mask_kernel<<<(dim + block - 1) / block, block, 0, stream>>>(
            S, mask, dim);

        // Contiguous fast path: 2048 chunks (32 KB) per block.
        // 8192x4096: n_chunks = 8,388,608 -> grid = 4096, cpr = 1024 (%512==0).
        if ((cpr % 512) == 0 && (n_chunks % 2048) == 0 &&
            (n_chunks / 2048) <= 0x7fffffffLL) {
            const long long grid = n_chunks / 2048;
            parity_apply_contig<<<(int)grid, block, 0, stream>>>(
                (const uint4v*)h, (const uint4v*)mask, (uint4v*)out, cpr);
        } else {
            long long grid = (n_chunks + (long long)block * 8 - 1) /
                             ((long long)block * 8);
            if (grid < 1) grid = 1;
            parity_apply_kernel<<<(int)grid, block, 0, stream>>>(
                (const uint4v*)h, (const uint4v*)mask, (uint4v*)out, cpr, n_chunks);
        }
    } else {
        int grid = 2048;
        if ((long long)grid * block > n_chunks) {
            grid = (int)((n_chunks + block - 1) / block);
            if (grid < 1) grid = 1;
        }
        parity_fallback_kernel<<<grid, block, 0, stream>>>(h, S, out, dim, n_chunks);
    }
}